// Round 1
// baseline (51587.079 us; speedup 1.0000x reference)
//
#include <hip/hip_runtime.h>
#include <hip/hip_bf16.h>
#include <math.h>

typedef unsigned int u32;
typedef unsigned long long u64;
typedef unsigned short u16;

#define NB 16
#define NPRED 25200
#define ND 85
#define NCLS 80
#define KDET 300
#define PPTS 128
#define NINST (NB*KDET)
#define CONF_T 0.2f
#define IOU_T 0.3f
#define MAX_WH_ 4096.0f
#define NBKT 8192

__device__ __forceinline__ float bflo(u32 u){ return __uint_as_float(u << 16); }
__device__ __forceinline__ float bfhi(u32 u){ return __uint_as_float(u & 0xffff0000u); }

// ---------------- stage 1: per-box score & class ----------------
__global__ __launch_bounds__(256) void k_score(const float* __restrict__ pred,
        float* __restrict__ score, int* __restrict__ cls){
  int i = blockIdx.x*256 + threadIdx.x;
  if (i >= NB*NPRED) return;
  const float* r = pred + (size_t)i*ND;
  float obj = r[4];
  float best = obj*r[5]; int bc = 0;
  for (int c = 1; c < NCLS; ++c){
    float v = obj*r[5+c];
    if (v > best){ best = v; bc = c; }   // strict > keeps first max (jnp.argmax)
  }
  score[i] = (best > CONF_T) ? best : 0.f;
  cls[i] = bc;
}

// ---------------- stage 2: exact top-300 per batch (histogram select + bitonic) ----------------
__global__ __launch_bounds__(1024) void k_topk(const float* __restrict__ score,
        int* __restrict__ top_i, float* __restrict__ top_s){
  __shared__ int hist[NBKT];
  __shared__ int part[1024];
  __shared__ u64 keys[1024];
  __shared__ int s_bstar, s_cnt;
  int b = blockIdx.x, t = threadIdx.x;
  const float* s = score + (size_t)b*NPRED;
  for (int i = t; i < NBKT; i += 1024) hist[i] = 0;
  __syncthreads();
  for (int i = t; i < NPRED; i += 1024){
    float v = s[i];
    if (v > 0.f){
      int bk = (int)(v * (float)NBKT); if (bk > NBKT-1) bk = NBKT-1;
      atomicAdd(&hist[bk], 1);
    }
  }
  __syncthreads();
  int psum = 0;
  for (int j = 0; j < 8; ++j) psum += hist[t*8+j];
  part[t] = psum;
  __syncthreads();
  if (t == 0){
    int cum = 0, bstar = 0;
    for (int q = 1023; q >= 0; --q){
      if (cum + part[q] >= KDET){
        int c2 = cum; int bb;
        for (bb = q*8+7; bb >= q*8; --bb){
          c2 += hist[bb];
          if (c2 >= KDET) break;
        }
        if (bb < q*8) bb = q*8;
        bstar = bb;
        break;
      }
      cum += part[q];
    }
    s_bstar = bstar;
    s_cnt = 0;
  }
  keys[t] = 0ull;
  __syncthreads();
  int bstar = s_bstar;
  for (int i = t; i < NPRED; i += 1024){
    float v = s[i];
    if (v > 0.f){
      int bk = (int)(v * (float)NBKT); if (bk > NBKT-1) bk = NBKT-1;
      if (bk >= bstar){
        int pos = atomicAdd(&s_cnt, 1);
        if (pos < 1024){
          // key: (score bits, ~index) -> descending sort == (score desc, index asc) like lax.top_k
          keys[pos] = ((u64)__float_as_uint(v) << 32) | (u32)(~(u32)i);
        }
      }
    }
  }
  __syncthreads();
  for (int k = 2; k <= 1024; k <<= 1){
    for (int j = k>>1; j > 0; j >>= 1){
      int ixj = t ^ j;
      if (ixj > t){
        u64 a = keys[t], c = keys[ixj];
        bool up = ((t & k) == 0);
        bool sw = up ? (a < c) : (a > c);   // descending
        if (sw){ keys[t] = c; keys[ixj] = a; }
      }
      __syncthreads();
    }
  }
  if (t < KDET){
    u64 key = keys[t];
    float v; int idx;
    if (key == 0ull){ v = 0.f; idx = 0; }
    else { v = __uint_as_float((u32)(key >> 32)); idx = (int)(~(u32)(key & 0xffffffffull)); }
    top_s[b*KDET + t] = v;
    top_i[b*KDET + t] = idx;
  }
}

// ---------------- stage 3: greedy class-aware NMS + box geometry + pts init ----------------
__global__ __launch_bounds__(384) void k_nms(const float* __restrict__ pred,
        const int* __restrict__ top_i, const float* __restrict__ top_s,
        const int* __restrict__ clsb,
        float* __restrict__ det_out, float* __restrict__ ct_out, float* __restrict__ pts_out,
        float* __restrict__ ct_ws, float* __restrict__ half_ws, int* __restrict__ valid_ws){
  __shared__ float bx0[KDET], bx1[KDET], bx2[KDET], bx3[KDET], ar[KDET];
  __shared__ float rx0[KDET], rx1[KDET], rx2[KDET], rx3[KDET];
  __shared__ float sc[KDET], cl[KDET];
  __shared__ float ctxs[KDET], ctys[KDET], hxs[KDET], hys[KDET];
  __shared__ int keep[KDET];
  int b = blockIdx.x, t = threadIdx.x;
  for (int i = t; i < KDET; i += 384){
    int idx = top_i[b*KDET + i];
    const float* r = pred + ((size_t)b*NPRED + idx)*ND;
    float cx = r[0], cy = r[1], w = r[2], h = r[3];
    float x1 = cx - w/2.f, y1 = cy - h/2.f, x2 = cx + w/2.f, y2 = cy + h/2.f;
    float c = (float)clsb[(size_t)b*NPRED + idx];
    float o = c * MAX_WH_;
    // offset boxes (rounding of +o replicated exactly like reference)
    float a0 = x1 + o, a1 = y1 + o, a2 = x2 + o, a3 = y2 + o;
    bx0[i]=a0; bx1[i]=a1; bx2[i]=a2; bx3[i]=a3;
    ar[i] = (a2-a0)*(a3-a1);
    rx0[i]=x1; rx1[i]=y1; rx2[i]=x2; rx3[i]=y2;
    sc[i] = top_s[b*KDET + i];
    cl[i] = c;
    keep[i] = 1;
  }
  __syncthreads();
  for (int i = 0; i < KDET; ++i){
    if (keep[i]){
      float b0=bx0[i], b1=bx1[i], b2=bx2[i], b3=bx3[i], ai=ar[i];
      for (int j = i+1+t; j < KDET; j += 384){
        float ltx = fmaxf(b0, bx0[j]);
        float lty = fmaxf(b1, bx1[j]);
        float rbx = fminf(b2, bx2[j]);
        float rby = fminf(b3, bx3[j]);
        float ww = rbx - ltx; ww = ww > 0.f ? ww : 0.f;
        float hh = rby - lty; hh = hh > 0.f ? hh : 0.f;
        float inter = ww*hh;
        float iou = inter / (ai + ar[j] - inter + 1e-9f);
        if (iou > IOU_T) keep[j] = 0;
      }
    }
    __syncthreads();
  }
  for (int i = t; i < KDET; i += 384){
    int v = (keep[i] && (sc[i] > CONF_T)) ? 1 : 0;
    valid_ws[b*KDET + i] = v;
    size_t o6 = ((size_t)b*KDET + i)*6;
    det_out[o6+0]=rx0[i]; det_out[o6+1]=rx1[i]; det_out[o6+2]=rx2[i]; det_out[o6+3]=rx3[i];
    det_out[o6+4]=sc[i];  det_out[o6+5]=cl[i];
    float bd0 = rx0[i]/4.f, bd1 = rx1[i]/4.f, bd2 = rx2[i]/4.f, bd3 = rx3[i]/4.f;
    float cx = (bd0+bd2)/2.f, cy = (bd1+bd3)/2.f;
    float hx = (bd2-bd0)/2.f; hx = hx > 1e-3f ? hx : 1e-3f;
    float hy = (bd3-bd1)/2.f; hy = hy > 1e-3f ? hy : 1e-3f;
    ct_out[((size_t)b*KDET+i)*2+0] = cx;
    ct_out[((size_t)b*KDET+i)*2+1] = cy;
    ct_ws[((size_t)b*KDET+i)*2+0] = cx;
    ct_ws[((size_t)b*KDET+i)*2+1] = cy;
    half_ws[((size_t)b*KDET+i)*2+0] = hx;
    half_ws[((size_t)b*KDET+i)*2+1] = hy;
    ctxs[i]=cx; ctys[i]=cy; hxs[i]=hx; hys[i]=hy;
  }
  __syncthreads();
  for (int e = t; e < KDET*PPTS; e += 384){
    int i = e >> 7, p = e & 127;
    float th = (float)p * 0.04908738521234052f;   // 2*pi/128 as f32 (matches jax weak-typed scalar)
    size_t o = ((size_t)(b*KDET + i)*PPTS + p)*2;
    pts_out[o+0] = ctxs[i] + hxs[i]*cosf(th);
    pts_out[o+1] = ctys[i] + hys[i]*sinf(th);
  }
}

// ---------------- stage 4: upsample2x(linear, half-pixel) + 3x3 conv + SiLU -> cf (bf16) ----------------
__global__ __launch_bounds__(256) void k_cnn(const float* __restrict__ feat,
        const float* __restrict__ cw, const float* __restrict__ cb,
        __hip_bfloat16* __restrict__ cf){
  __shared__ float up[324];    // 18x18 upsampled tile for one in-channel
  __shared__ float wl[576];    // 64 oc x 9 taps for one in-channel
  int b = blockIdx.x;
  int tile = blockIdx.y;
  int ty0 = (tile/10)*16, tx0 = (tile - (tile/10)*10)*16;
  int t = threadIdx.x;
  int py = t >> 4, px = t & 15;
  int oy = ty0 + py, ox = tx0 + px;
  float acc[64];
  #pragma unroll
  for (int o = 0; o < 64; ++o) acc[o] = 0.f;
  for (int ic = 0; ic < 128; ++ic){
    __syncthreads();
    const float* fin = feat + ((size_t)b*128 + ic)*6400;
    for (int u = t; u < 324; u += 256){
      int r = u/18;
      int uy = ty0 - 1 + r, ux = tx0 - 1 + (u - r*18);
      float val = 0.f;                        // conv SAME zero-pad outside [0,160)
      if (uy >= 0 && uy < 160 && ux >= 0 && ux < 160){
        float cyf = 0.5f*(float)uy - 0.25f;   // half-pixel mapping; edge clamp == jax renorm
        float cxf = 0.5f*(float)ux - 0.25f;
        float fy0 = floorf(cyf), fx0 = floorf(cxf);
        float fy = cyf - fy0, fx = cxf - fx0;
        int y0 = (int)fy0, x0 = (int)fx0;
        int y0c = y0 < 0 ? 0 : (y0 > 79 ? 79 : y0);
        int y1c = y0+1 > 79 ? 79 : (y0+1 < 0 ? 0 : y0+1);
        int x0c = x0 < 0 ? 0 : (x0 > 79 ? 79 : x0);
        int x1c = x0+1 > 79 ? 79 : (x0+1 < 0 ? 0 : x0+1);
        float v00 = fin[y0c*80+x0c], v01 = fin[y0c*80+x1c];
        float v10 = fin[y1c*80+x0c], v11 = fin[y1c*80+x1c];
        val = v00*(1.f-fy)*(1.f-fx) + v01*(1.f-fy)*fx + v10*fy*(1.f-fx) + v11*fy*fx;
      }
      up[u] = val;
    }
    for (int u = t; u < 576; u += 256){
      int o = u/9;
      wl[u] = cw[((size_t)o*128 + ic)*9 + (u - o*9)];
    }
    __syncthreads();
    float v[9];
    #pragma unroll
    for (int k = 0; k < 9; ++k)
      v[k] = up[(py + k/3)*18 + (px + k%3)];
    #pragma unroll
    for (int o = 0; o < 64; ++o){
      float a = acc[o];
      #pragma unroll
      for (int k = 0; k < 9; ++k) a += wl[o*9+k]*v[k];
      acc[o] = a;
    }
  }
  size_t base = ((size_t)b*64)*25600 + (size_t)oy*160 + ox;
  #pragma unroll
  for (int o = 0; o < 64; ++o){
    float x = acc[o] + cb[o];
    float sg = 1.f / (1.f + __expf(-x));
    cf[base + (size_t)o*25600] = __float2bfloat16(x*sg);
  }
}

// ---------------- stage 5: bilinear sample + rel -> z channels of states ----------------
__global__ __launch_bounds__(256) void k_sample(const __hip_bfloat16* __restrict__ cf,
        const float* __restrict__ pts, const float* __restrict__ ct_ws,
        const float* __restrict__ half_ws, __hip_bfloat16* __restrict__ states,
        int base, int cnt){
  int e = blockIdx.x*256 + threadIdx.x;
  if (e >= cnt*PPTS) return;
  int li = e >> 7, p = e & 127;
  int g = base + li;
  int b = g / KDET;
  size_t po = ((size_t)g*PPTS + p)*2;
  float px = pts[po], py = pts[po+1];
  float ctx = ct_ws[g*2], cty = ct_ws[g*2+1];
  float hx = half_ws[g*2], hy = half_ws[g*2+1];
  __hip_bfloat16* st = states + (size_t)li*1090*128;
  st[64*128 + p] = __float2bfloat16((px - ctx)/hx);
  st[65*128 + p] = __float2bfloat16((py - cty)/hy);
  float x = px < 0.f ? 0.f : (px > 159.f ? 159.f : px);
  float y = py < 0.f ? 0.f : (py > 159.f ? 159.f : py);
  float x0f = floorf(x); x0f = x0f < 0.f ? 0.f : (x0f > 158.f ? 158.f : x0f);
  float y0f = floorf(y); y0f = y0f < 0.f ? 0.f : (y0f > 158.f ? 158.f : y0f);
  float dx = x - x0f, dy = y - y0f;
  int x0 = (int)x0f, y0 = (int)y0f;
  float w00 = (1.f-dx)*(1.f-dy), w01 = dx*(1.f-dy), w10 = (1.f-dx)*dy, w11 = dx*dy;
  const __hip_bfloat16* f = cf + (size_t)b*64*25600 + (size_t)y0*160 + x0;
  for (int c = 0; c < 64; ++c){
    const __hip_bfloat16* fc = f + (size_t)c*25600;
    float v00 = __bfloat162float(fc[0]);
    float v01 = __bfloat162float(fc[1]);
    float v10 = __bfloat162float(fc[160]);
    float v11 = __bfloat162float(fc[161]);
    st[c*128 + p] = __float2bfloat16(v00*w00 + v01*w01 + v10*w10 + v11*w11);
  }
}

// ---------------- stage 6: circular conv1d k=9 (head / dilated res blocks) ----------------
// block = one instance, 512 thr: oc = t&127, point-quarter = t>>7 (32 pts each).
// LDS holds input tile bf16, circularly padded to 160 cols: col j <-> x[(j-16)&127].
template<int CI, int DIL, bool SKIP>
__global__ __launch_bounds__(512) void k_conv1d(__hip_bfloat16* __restrict__ states,
        const float* __restrict__ wr,      // repacked [CI][9][128oc]
        const float* __restrict__ bias,    // [128]
        int in_off, int out_off){
  extern __shared__ u16 xlb[];
  constexpr int W = 32 + 8*DIL;
  int inst = blockIdx.x;
  const u16* sin16 = (const u16*)states + (size_t)inst*1090*128 + (size_t)in_off*128;
  int t = threadIdx.x;
  for (int j = t; j < CI*160; j += 512){
    int ic = j / 160, jj = j - ic*160;
    xlb[j] = sin16[ic*128 + ((jj + 112) & 127)];
  }
  __syncthreads();
  int oc = t & 127, pq = t >> 7;
  int p0 = pq*32;
  float acc[32];
  float bv = bias[oc];
  #pragma unroll
  for (int j = 0; j < 32; ++j) acc[j] = bv;
  const int wbase = 16 + p0 - 4*DIL;      // always >= 0, window fits [0,160)
  for (int ic = 0; ic < CI; ++ic){
    float xv[W];
    const u16* row = &xlb[ic*160 + wbase];
    #pragma unroll
    for (int i = 0; i < W; i += 4){
      uint2 u = *(const uint2*)(row + i);
      xv[i]   = bflo(u.x);
      xv[i+1] = bfhi(u.x);
      xv[i+2] = bflo(u.y);
      xv[i+3] = bfhi(u.y);
    }
    const float* wrow = wr + (size_t)ic*1152 + oc;
    #pragma unroll
    for (int k = 0; k < 9; ++k){
      float w = wrow[k*128];
      #pragma unroll
      for (int j = 0; j < 32; ++j)
        acc[j] += w*xv[j + k*DIL];
    }
  }
  __hip_bfloat16* so = states + (size_t)inst*1090*128 + (size_t)out_off*128 + (size_t)oc*128 + p0;
  const u16* srow = &xlb[oc*160 + 16 + p0];
  #pragma unroll
  for (int j = 0; j < 32; j += 4){
    float v0 = acc[j]   > 0.f ? acc[j]   : 0.f;
    float v1 = acc[j+1] > 0.f ? acc[j+1] : 0.f;
    float v2 = acc[j+2] > 0.f ? acc[j+2] : 0.f;
    float v3 = acc[j+3] > 0.f ? acc[j+3] : 0.f;
    if (SKIP){
      uint2 u = *(const uint2*)(srow + j);
      v0 += bflo(u.x); v1 += bfhi(u.x); v2 += bflo(u.y); v3 += bfhi(u.y);
    }
    so[j]   = __float2bfloat16(v0);
    so[j+1] = __float2bfloat16(v1);
    so[j+2] = __float2bfloat16(v2);
    so[j+3] = __float2bfloat16(v3);
  }
}

// ---------------- stage 7: fuse 1x1 (1090 -> 256) as tiled f32 GEMM, relu -> fusedbuf bf16 ----------------
__global__ __launch_bounds__(256) void k_fuse(const __hip_bfloat16* __restrict__ states,
        const float* __restrict__ wfr,   // repacked [1090][256]
        const float* __restrict__ bfuse,
        __hip_bfloat16* __restrict__ fusedbuf){
  __shared__ float As[8][128];
  __shared__ float Bs[8][128];
  int inst = blockIdx.x, mb = blockIdx.y;
  int t = threadIdx.x;
  int tx = t & 15, ty = t >> 4;
  const u16* st = (const u16*)(states + (size_t)inst*1090*128);
  float acc[8][8];
  #pragma unroll
  for (int i = 0; i < 8; ++i)
    #pragma unroll
    for (int j = 0; j < 8; ++j) acc[i][j] = 0.f;
  for (int k0 = 0; k0 < 1090; k0 += 8){
    __syncthreads();
    for (int i = t; i < 1024; i += 256){
      int kk = i >> 7, c = i & 127;
      int kr = k0 + kk;
      bool ok = kr < 1090;
      As[kk][c] = ok ? wfr[(size_t)kr*256 + mb*128 + c] : 0.f;
      Bs[kk][c] = ok ? bflo((u32)st[(size_t)kr*128 + c]) : 0.f;
    }
    __syncthreads();
    #pragma unroll
    for (int kk = 0; kk < 8; ++kk){
      float a[8], bb[8];
      #pragma unroll
      for (int i = 0; i < 8; ++i) a[i] = As[kk][ty*8+i];
      #pragma unroll
      for (int j = 0; j < 8; ++j) bb[j] = Bs[kk][tx*8+j];
      #pragma unroll
      for (int i = 0; i < 8; ++i)
        #pragma unroll
        for (int j = 0; j < 8; ++j)
          acc[i][j] += a[i]*bb[j];
    }
  }
  __hip_bfloat16* fo = fusedbuf + (size_t)inst*256*128;
  #pragma unroll
  for (int i = 0; i < 8; ++i){
    int oc = mb*128 + ty*8 + i;
    float bv = bfuse[oc];
    #pragma unroll
    for (int j = 0; j < 8; ++j){
      float v = acc[i][j] + bv;
      fo[(size_t)oc*128 + tx*8 + j] = __float2bfloat16(v > 0.f ? v : 0.f);
    }
  }
}

// ---------------- stage 8: p1 (256->64, relu) + p2 (64->2) + pts update ----------------
__global__ __launch_bounds__(128) void k_p1p2(const __hip_bfloat16* __restrict__ fusedbuf,
        const float* __restrict__ wp1r,  // repacked [256][64]
        const float* __restrict__ bp1,
        const float* __restrict__ wp2,   // [2][64]
        const float* __restrict__ bp2,
        float* __restrict__ pts, int base){
  int inst = blockIdx.x, p = threadIdx.x;
  const u16* f = (const u16*)(fusedbuf + (size_t)inst*256*128);
  float h[64];
  #pragma unroll
  for (int o = 0; o < 64; ++o) h[o] = bp1[o];
  for (int ic = 0; ic < 256; ++ic){
    float x = bflo((u32)f[(size_t)ic*128 + p]);
    const float* w = wp1r + (size_t)ic*64;
    #pragma unroll
    for (int o = 0; o < 64; ++o) h[o] += w[o]*x;
  }
  float ox = bp2[0], oy = bp2[1];
  #pragma unroll
  for (int o = 0; o < 64; ++o){
    float hv = h[o] > 0.f ? h[o] : 0.f;
    ox += wp2[o]*hv;
    oy += wp2[64+o]*hv;
  }
  int g = base + inst;
  size_t po = ((size_t)g*PPTS + p)*2;
  pts[po]   += ox;
  pts[po+1] += oy;
}

// ---------------- stage 9: mask pts by valid; write valid as float ----------------
__global__ __launch_bounds__(256) void k_final(float* __restrict__ pts,
        const int* __restrict__ valid_ws, float* __restrict__ valid_out){
  int e = blockIdx.x*256 + threadIdx.x;
  if (e < NINST) valid_out[e] = valid_ws[e] ? 1.f : 0.f;
  if (e < NINST*PPTS){
    float m = valid_ws[e >> 7] ? 1.f : 0.f;
    pts[(size_t)e*2]   *= m;
    pts[(size_t)e*2+1] *= m;
  }
}

// ---------------- weight repacks (run each call; cheap, graph-safe) ----------------
__global__ __launch_bounds__(256) void k_repack_head(const float* __restrict__ w, float* __restrict__ wr){
  int e = blockIdx.x*256 + threadIdx.x;
  if (e >= 128*66*9) return;
  int oc = e / 594, r = e - oc*594;
  int ic = r / 9, k = r - ic*9;
  wr[(ic*9 + k)*128 + oc] = w[e];
}
__global__ __launch_bounds__(256) void k_repack_res(const float* __restrict__ w, float* __restrict__ wr){
  int e = blockIdx.x*256 + threadIdx.x;
  if (e >= 7*128*128*9) return;
  int l = e / 147456, r = e - l*147456;
  int oc = r / 1152, r2 = r - oc*1152;
  int ic = r2 / 9, k = r2 - ic*9;
  wr[(((size_t)l*128 + ic)*9 + k)*128 + oc] = w[e];
}
__global__ __launch_bounds__(256) void k_repack_fuse(const float* __restrict__ w, float* __restrict__ wr){
  int e = blockIdx.x*256 + threadIdx.x;
  if (e >= 256*1090) return;
  int oc = e / 1090, ic = e - oc*1090;
  wr[(size_t)ic*256 + oc] = w[e];
}
__global__ __launch_bounds__(256) void k_repack_p1(const float* __restrict__ w, float* __restrict__ wr){
  int e = blockIdx.x*256 + threadIdx.x;
  if (e >= 64*256) return;
  int oc = e / 256, ic = e - oc*256;
  wr[ic*64 + oc] = w[e];
}

extern "C" void kernel_launch(void* const* d_in, const int* in_sizes, int n_in,
                              void* d_out, int out_size, void* d_ws, size_t ws_size,
                              hipStream_t stream){
  (void)in_sizes; (void)n_in; (void)out_size;
  const float* pred   = (const float*)d_in[0];
  const float* feat   = (const float*)d_in[1];
  const float* conv_w = (const float*)d_in[2];
  const float* conv_b = (const float*)d_in[3];
  const float* w_head = (const float*)d_in[4];
  const float* b_head = (const float*)d_in[5];
  const float* w_res  = (const float*)d_in[6];
  const float* b_res  = (const float*)d_in[7];
  const float* w_fuse = (const float*)d_in[8];
  const float* b_fuse = (const float*)d_in[9];
  const float* w_p1   = (const float*)d_in[10];
  const float* b_p1   = (const float*)d_in[11];
  const float* w_p2   = (const float*)d_in[12];
  const float* b_p2   = (const float*)d_in[13];

  float* out = (float*)d_out;
  float* det_out   = out;             // [16][300][6]
  float* ct_out    = out + 28800;     // [16][300][2]
  float* pts_out   = out + 38400;     // [16][300][128][2] (also working buffer)
  float* valid_out = out + 1267200;   // [16][300]

  char* wsb = (char*)d_ws;
  size_t woff = 0;
  auto walloc = [&](size_t bytes)->char*{
    char* p = wsb + woff;
    woff += (bytes + 255) & ~(size_t)255;
    return p;
  };
  __hip_bfloat16* cf = (__hip_bfloat16*)walloc((size_t)16*64*160*160*2);
  float* score   = (float*)walloc((size_t)NB*NPRED*4);
  int*   clsb    = (int*)  walloc((size_t)NB*NPRED*4);
  int*   top_i   = (int*)  walloc((size_t)NINST*4);
  float* top_s   = (float*)walloc((size_t)NINST*4);
  float* ct_ws   = (float*)walloc((size_t)NINST*2*4);
  float* half_ws = (float*)walloc((size_t)NINST*2*4);
  int*   valid_ws= (int*)  walloc((size_t)NINST*4);
  float* wr_head = (float*)walloc((size_t)76032*4);
  float* wr_res  = (float*)walloc((size_t)1032192*4);
  float* wr_fuse = (float*)walloc((size_t)279040*4);
  float* wr_p1   = (float*)walloc((size_t)16384*4);

  // adaptive chunking: per-instance scratch = states(1090x128 bf16) + fused(256x128 bf16)
  size_t per_inst = (size_t)1090*128*2 + (size_t)256*128*2;
  long long avail = (long long)ws_size - (long long)woff;
  int C = (int)(avail / (long long)per_inst);
  if (C > 1200) C = 1200;
  if (C < 1) C = 1;
  __hip_bfloat16* states   = (__hip_bfloat16*)walloc((size_t)C*1090*128*2);
  __hip_bfloat16* fusedbuf = (__hip_bfloat16*)walloc((size_t)C*256*128*2);

  k_repack_head<<<(76032+255)/256, 256, 0, stream>>>(w_head, wr_head);
  k_repack_res <<<(1032192+255)/256, 256, 0, stream>>>(w_res, wr_res);
  k_repack_fuse<<<(279040+255)/256, 256, 0, stream>>>(w_fuse, wr_fuse);
  k_repack_p1  <<<(16384+255)/256, 256, 0, stream>>>(w_p1, wr_p1);

  k_score<<<(NB*NPRED+255)/256, 256, 0, stream>>>(pred, score, clsb);
  k_topk <<<NB, 1024, 0, stream>>>(score, top_i, top_s);
  k_nms  <<<NB, 384, 0, stream>>>(pred, top_i, top_s, clsb, det_out, ct_out, pts_out,
                                  ct_ws, half_ws, valid_ws);
  k_cnn  <<<dim3(16,100), 256, 0, stream>>>(feat, conv_w, conv_b, cf);

  static const int dils[7] = {1,1,1,2,2,4,4};
  for (int it = 0; it < 2; ++it){
    for (int base = 0; base < NINST; base += C){
      int cnt = NINST - base; if (cnt > C) cnt = C;
      k_sample<<<(cnt*PPTS+255)/256, 256, 0, stream>>>(cf, pts_out, ct_ws, half_ws, states, base, cnt);
      k_conv1d<66,1,false><<<cnt, 512, 66*160*2, stream>>>(states, wr_head, b_head, 0, 66);
      for (int l = 0; l < 7; ++l){
        const float* wl = wr_res + (size_t)l*147456;
        const float* bl = b_res + l*128;
        int io = 66 + 128*l, oo = 194 + 128*l;
        if (dils[l] == 1)
          k_conv1d<128,1,true><<<cnt, 512, 128*160*2, stream>>>(states, wl, bl, io, oo);
        else if (dils[l] == 2)
          k_conv1d<128,2,true><<<cnt, 512, 128*160*2, stream>>>(states, wl, bl, io, oo);
        else
          k_conv1d<128,4,true><<<cnt, 512, 128*160*2, stream>>>(states, wl, bl, io, oo);
      }
      k_fuse<<<dim3(cnt,2), 256, 0, stream>>>(states, wr_fuse, b_fuse, fusedbuf);
      k_p1p2<<<cnt, 128, 0, stream>>>(fusedbuf, wr_p1, b_p1, w_p2, b_p2, pts_out, base);
    }
  }
  k_final<<<(NINST*PPTS+255)/256, 256, 0, stream>>>(pts_out, valid_ws, valid_out);
}

// Round 4
// 10870.756 us; speedup vs baseline: 4.7455x; 4.7455x over previous
//
#include <hip/hip_runtime.h>
#include <hip/hip_bf16.h>
#include <math.h>

typedef unsigned int u32;
typedef unsigned long long u64;
typedef unsigned short u16;

#define NB 16
#define NPRED 25200
#define ND 85
#define NCLS 80
#define KDET 300
#define PPTS 128
#define NINST (NB*KDET)
#define CONF_T 0.2f
#define IOU_T 0.3f
#define MAX_WH_ 4096.0f
#define NBKT 8192

// states layout per instance: [p=128][ch=1120] bf16
//   ch 0..127    : head conv output      (orig fuse channels 66..193)
//   ch 128*(l+1) : res block l output    (orig 194+128l .. )
//   ch 1024..1089: z = [feats(64), relx, rely]  (orig 0..65)
//   ch 1090..1119: pad (zero weights)
#define CH 1120
#define STROW 143360   // 128*1120 u16 per instance

typedef __attribute__((ext_vector_type(8))) short bhalf8;
typedef __attribute__((ext_vector_type(4))) float f32x4;

__device__ __forceinline__ float b2f(u16 u){ return __uint_as_float((u32)u << 16); }
__device__ __forceinline__ u16 f2b(float v){ __hip_bfloat16 h = __float2bfloat16(v); return *(u16*)&h; }

// ---------------- stage 1: per-box score & class ----------------
__global__ __launch_bounds__(256) void k_score(const float* __restrict__ pred,
        float* __restrict__ score, int* __restrict__ cls){
  int i = blockIdx.x*256 + threadIdx.x;
  if (i >= NB*NPRED) return;
  const float* r = pred + (size_t)i*ND;
  float obj = r[4];
  float best = obj*r[5]; int bc = 0;
  for (int c = 1; c < NCLS; ++c){
    float v = obj*r[5+c];
    if (v > best){ best = v; bc = c; }
  }
  score[i] = (best > CONF_T) ? best : 0.f;
  cls[i] = bc;
}

// ---------------- stage 2: exact top-300 per batch ----------------
__global__ __launch_bounds__(1024) void k_topk(const float* __restrict__ score,
        int* __restrict__ top_i, float* __restrict__ top_s){
  __shared__ int hist[NBKT];
  __shared__ int part[1024];
  __shared__ u64 keys[1024];
  __shared__ int s_bstar, s_cnt;
  int b = blockIdx.x, t = threadIdx.x;
  const float* s = score + (size_t)b*NPRED;
  for (int i = t; i < NBKT; i += 1024) hist[i] = 0;
  __syncthreads();
  for (int i = t; i < NPRED; i += 1024){
    float v = s[i];
    if (v > 0.f){
      int bk = (int)(v * (float)NBKT); if (bk > NBKT-1) bk = NBKT-1;
      atomicAdd(&hist[bk], 1);
    }
  }
  __syncthreads();
  int psum = 0;
  for (int j = 0; j < 8; ++j) psum += hist[t*8+j];
  part[t] = psum;
  __syncthreads();
  if (t == 0){
    int cum = 0, bstar = 0;
    for (int q = 1023; q >= 0; --q){
      if (cum + part[q] >= KDET){
        int c2 = cum; int bb;
        for (bb = q*8+7; bb >= q*8; --bb){
          c2 += hist[bb];
          if (c2 >= KDET) break;
        }
        if (bb < q*8) bb = q*8;
        bstar = bb;
        break;
      }
      cum += part[q];
    }
    s_bstar = bstar;
    s_cnt = 0;
  }
  keys[t] = 0ull;
  __syncthreads();
  int bstar = s_bstar;
  for (int i = t; i < NPRED; i += 1024){
    float v = s[i];
    if (v > 0.f){
      int bk = (int)(v * (float)NBKT); if (bk > NBKT-1) bk = NBKT-1;
      if (bk >= bstar){
        int pos = atomicAdd(&s_cnt, 1);
        if (pos < 1024){
          keys[pos] = ((u64)__float_as_uint(v) << 32) | (u32)(~(u32)i);
        }
      }
    }
  }
  __syncthreads();
  for (int k = 2; k <= 1024; k <<= 1){
    for (int j = k>>1; j > 0; j >>= 1){
      int ixj = t ^ j;
      if (ixj > t){
        u64 a = keys[t], c = keys[ixj];
        bool up = ((t & k) == 0);
        bool sw = up ? (a < c) : (a > c);
        if (sw){ keys[t] = c; keys[ixj] = a; }
      }
      __syncthreads();
    }
  }
  if (t < KDET){
    u64 key = keys[t];
    float v; int idx;
    if (key == 0ull){ v = 0.f; idx = 0; }
    else { v = __uint_as_float((u32)(key >> 32)); idx = (int)(~(u32)(key & 0xffffffffull)); }
    top_s[b*KDET + t] = v;
    top_i[b*KDET + t] = idx;
  }
}

// ---------------- stage 3: NMS + box geometry + pts init ----------------
__global__ __launch_bounds__(384) void k_nms(const float* __restrict__ pred,
        const int* __restrict__ top_i, const float* __restrict__ top_s,
        const int* __restrict__ clsb,
        float* __restrict__ det_out, float* __restrict__ ct_out, float* __restrict__ pts_out,
        float* __restrict__ ct_ws, float* __restrict__ half_ws, int* __restrict__ valid_ws){
  __shared__ float bx0[KDET], bx1[KDET], bx2[KDET], bx3[KDET], ar[KDET];
  __shared__ float rx0[KDET], rx1[KDET], rx2[KDET], rx3[KDET];
  __shared__ float sc[KDET], cl[KDET];
  __shared__ float ctxs[KDET], ctys[KDET], hxs[KDET], hys[KDET];
  __shared__ int keep[KDET];
  int b = blockIdx.x, t = threadIdx.x;
  for (int i = t; i < KDET; i += 384){
    int idx = top_i[b*KDET + i];
    const float* r = pred + ((size_t)b*NPRED + idx)*ND;
    float cx = r[0], cy = r[1], w = r[2], h = r[3];
    float x1 = cx - w/2.f, y1 = cy - h/2.f, x2 = cx + w/2.f, y2 = cy + h/2.f;
    float c = (float)clsb[(size_t)b*NPRED + idx];
    float o = c * MAX_WH_;
    float a0 = x1 + o, a1 = y1 + o, a2 = x2 + o, a3 = y2 + o;
    bx0[i]=a0; bx1[i]=a1; bx2[i]=a2; bx3[i]=a3;
    ar[i] = (a2-a0)*(a3-a1);
    rx0[i]=x1; rx1[i]=y1; rx2[i]=x2; rx3[i]=y2;
    sc[i] = top_s[b*KDET + i];
    cl[i] = c;
    keep[i] = 1;
  }
  __syncthreads();
  for (int i = 0; i < KDET; ++i){
    if (keep[i]){
      float b0=bx0[i], b1=bx1[i], b2=bx2[i], b3=bx3[i], ai=ar[i];
      for (int j = i+1+t; j < KDET; j += 384){
        float ltx = fmaxf(b0, bx0[j]);
        float lty = fmaxf(b1, bx1[j]);
        float rbx = fminf(b2, bx2[j]);
        float rby = fminf(b3, bx3[j]);
        float ww = rbx - ltx; ww = ww > 0.f ? ww : 0.f;
        float hh = rby - lty; hh = hh > 0.f ? hh : 0.f;
        float inter = ww*hh;
        float iou = inter / (ai + ar[j] - inter + 1e-9f);
        if (iou > IOU_T) keep[j] = 0;
      }
    }
    __syncthreads();
  }
  for (int i = t; i < KDET; i += 384){
    int v = (keep[i] && (sc[i] > CONF_T)) ? 1 : 0;
    valid_ws[b*KDET + i] = v;
    size_t o6 = ((size_t)b*KDET + i)*6;
    det_out[o6+0]=rx0[i]; det_out[o6+1]=rx1[i]; det_out[o6+2]=rx2[i]; det_out[o6+3]=rx3[i];
    det_out[o6+4]=sc[i];  det_out[o6+5]=cl[i];
    float bd0 = rx0[i]/4.f, bd1 = rx1[i]/4.f, bd2 = rx2[i]/4.f, bd3 = rx3[i]/4.f;
    float cx = (bd0+bd2)/2.f, cy = (bd1+bd3)/2.f;
    float hx = (bd2-bd0)/2.f; hx = hx > 1e-3f ? hx : 1e-3f;
    float hy = (bd3-bd1)/2.f; hy = hy > 1e-3f ? hy : 1e-3f;
    ct_out[((size_t)b*KDET+i)*2+0] = cx;
    ct_out[((size_t)b*KDET+i)*2+1] = cy;
    ct_ws[((size_t)b*KDET+i)*2+0] = cx;
    ct_ws[((size_t)b*KDET+i)*2+1] = cy;
    half_ws[((size_t)b*KDET+i)*2+0] = hx;
    half_ws[((size_t)b*KDET+i)*2+1] = hy;
    ctxs[i]=cx; ctys[i]=cy; hxs[i]=hx; hys[i]=hy;
  }
  __syncthreads();
  for (int e = t; e < KDET*PPTS; e += 384){
    int i = e >> 7, p = e & 127;
    float th = (float)p * 0.04908738521234052f;
    size_t o = ((size_t)(b*KDET + i)*PPTS + p)*2;
    pts_out[o+0] = ctxs[i] + hxs[i]*cosf(th);
    pts_out[o+1] = ctys[i] + hys[i]*sinf(th);
  }
}

// ---------------- stage 4: upsample2x + 3x3 conv + SiLU -> cf (bf16) ----------------
__global__ __launch_bounds__(256) void k_cnn(const float* __restrict__ feat,
        const float* __restrict__ cw, const float* __restrict__ cb,
        __hip_bfloat16* __restrict__ cf){
  __shared__ float up[324];
  __shared__ float wl[576];
  int b = blockIdx.x;
  int tile = blockIdx.y;
  int ty0 = (tile/10)*16, tx0 = (tile - (tile/10)*10)*16;
  int t = threadIdx.x;
  int py = t >> 4, px = t & 15;
  int oy = ty0 + py, ox = tx0 + px;
  float acc[64];
  #pragma unroll
  for (int o = 0; o < 64; ++o) acc[o] = 0.f;
  for (int ic = 0; ic < 128; ++ic){
    __syncthreads();
    const float* fin = feat + ((size_t)b*128 + ic)*6400;
    for (int u = t; u < 324; u += 256){
      int r = u/18;
      int uy = ty0 - 1 + r, ux = tx0 - 1 + (u - r*18);
      float val = 0.f;
      if (uy >= 0 && uy < 160 && ux >= 0 && ux < 160){
        float cyf = 0.5f*(float)uy - 0.25f;
        float cxf = 0.5f*(float)ux - 0.25f;
        float fy0 = floorf(cyf), fx0 = floorf(cxf);
        float fy = cyf - fy0, fx = cxf - fx0;
        int y0 = (int)fy0, x0 = (int)fx0;
        int y0c = y0 < 0 ? 0 : (y0 > 79 ? 79 : y0);
        int y1c = y0+1 > 79 ? 79 : (y0+1 < 0 ? 0 : y0+1);
        int x0c = x0 < 0 ? 0 : (x0 > 79 ? 79 : x0);
        int x1c = x0+1 > 79 ? 79 : (x0+1 < 0 ? 0 : x0+1);
        float v00 = fin[y0c*80+x0c], v01 = fin[y0c*80+x1c];
        float v10 = fin[y1c*80+x0c], v11 = fin[y1c*80+x1c];
        val = v00*(1.f-fy)*(1.f-fx) + v01*(1.f-fy)*fx + v10*fy*(1.f-fx) + v11*fy*fx;
      }
      up[u] = val;
    }
    for (int u = t; u < 576; u += 256){
      int o = u/9;
      wl[u] = cw[((size_t)o*128 + ic)*9 + (u - o*9)];
    }
    __syncthreads();
    float v[9];
    #pragma unroll
    for (int k = 0; k < 9; ++k)
      v[k] = up[(py + k/3)*18 + (px + k%3)];
    #pragma unroll
    for (int o = 0; o < 64; ++o){
      float a = acc[o];
      #pragma unroll
      for (int k = 0; k < 9; ++k) a += wl[o*9+k]*v[k];
      acc[o] = a;
    }
  }
  size_t base = ((size_t)b*64)*25600 + (size_t)oy*160 + ox;
  #pragma unroll
  for (int o = 0; o < 64; ++o){
    float x = acc[o] + cb[o];
    float sg = 1.f / (1.f + __expf(-x));
    cf[base + (size_t)o*25600] = __float2bfloat16(x*sg);
  }
}

// ---------------- stage 5: bilinear sample + rel -> z (ch 1024..1089) ----------------
__global__ __launch_bounds__(256) void k_sample(const __hip_bfloat16* __restrict__ cf,
        const float* __restrict__ pts, const float* __restrict__ ct_ws,
        const float* __restrict__ half_ws, __hip_bfloat16* __restrict__ states,
        int base, int cnt){
  int e = blockIdx.x*256 + threadIdx.x;
  if (e >= cnt*PPTS) return;
  int li = e >> 7, p = e & 127;
  int g = base + li;
  int b = g / KDET;
  size_t po = ((size_t)g*PPTS + p)*2;
  float px = pts[po], py = pts[po+1];
  float ctx = ct_ws[g*2], cty = ct_ws[g*2+1];
  float hx = half_ws[g*2], hy = half_ws[g*2+1];
  __align__(16) u16 zl[66];
  zl[64] = f2b((px - ctx)/hx);
  zl[65] = f2b((py - cty)/hy);
  float x = px < 0.f ? 0.f : (px > 159.f ? 159.f : px);
  float y = py < 0.f ? 0.f : (py > 159.f ? 159.f : py);
  float x0f = floorf(x); x0f = x0f < 0.f ? 0.f : (x0f > 158.f ? 158.f : x0f);
  float y0f = floorf(y); y0f = y0f < 0.f ? 0.f : (y0f > 158.f ? 158.f : y0f);
  float dx = x - x0f, dy = y - y0f;
  int x0 = (int)x0f, y0 = (int)y0f;
  float w00 = (1.f-dx)*(1.f-dy), w01 = dx*(1.f-dy), w10 = (1.f-dx)*dy, w11 = dx*dy;
  const __hip_bfloat16* f = cf + (size_t)b*64*25600 + (size_t)y0*160 + x0;
  for (int c = 0; c < 64; ++c){
    const __hip_bfloat16* fc = f + (size_t)c*25600;
    float v00 = __bfloat162float(fc[0]);
    float v01 = __bfloat162float(fc[1]);
    float v10 = __bfloat162float(fc[160]);
    float v11 = __bfloat162float(fc[161]);
    zl[c] = f2b(v00*w00 + v01*w01 + v10*w10 + v11*w11);
  }
  u16* dst = (u16*)states + ((size_t)li*128 + p)*CH + 1024;
  #pragma unroll
  for (int w2 = 0; w2 < 64; w2 += 8) *(uint4*)(dst + w2) = *(const uint4*)(zl + w2);
  *(u32*)(dst + 64) = *(const u32*)(zl + 64);
}

// ================= MFMA GEMM core =================
// LDS tile: [128 rows(p)][128 cols(ch)] bf16, 256B rows, byte ^= (row&7)<<4 swizzle.
// A-frag (16x16x32): lane l -> row = l&15 (+rg offset), k = (l>>4)*8 + j (j contiguous).
// B pre-packed in fragment order: [s][ct][lane][8].
// C (m89): col = lane&15, row = (lane>>4)*4 + reg.

template<int NSUB>
__device__ __forceinline__ void g_load_a(bhalf8* dst, const u16* Xb, int s, int dil,
                                         int rg0, int r16, int hi){
  int k = s / NSUB;
  int icb = (s - k*NSUB)*64 + hi*16;     // byte col base
  int shift = (k - 4)*dil;
  #pragma unroll
  for (int g = 0; g < 4; ++g){
    int row = (rg0 + g*16 + r16 + shift + 128) & 127;
    dst[g] = *(const bhalf8*)((const char*)Xb + row*256 + (icb ^ ((row & 7) << 4)));
  }
}
__device__ __forceinline__ void g_load_b(bhalf8* dst, const bhalf8* wf, int s, int lane, int sstride){
  const bhalf8* w = wf + (size_t)s*sstride + lane;
  #pragma unroll
  for (int ct = 0; ct < 8; ++ct) dst[ct] = w[ct*64];
}

#define MFMA_SET(A_, B_) { \
  _Pragma("unroll") \
  for (int g_ = 0; g_ < 4; ++g_){ \
    _Pragma("unroll") \
    for (int ct_ = 0; ct_ < 8; ++ct_) \
      acc[g_][ct_] = __builtin_amdgcn_mfma_f32_16x16x32_bf16((A_)[g_], (B_)[ct_], acc[g_][ct_], 0, 0, 0); \
  } }

template<int NSUB>
__device__ __forceinline__ void gemm_run(const u16* Xb, const bhalf8* wf, int s0, int s1,
    int dil, int rg0, int r16, int hi, int lane, f32x4 acc[4][8], int sstride){
  bhalf8 aA[4], bA[8], aB[4], bB[8];
  g_load_a<NSUB>(aA, Xb, s0, dil, rg0, r16, hi);
  g_load_b(bA, wf, s0, lane, sstride);
  int s = s0;
  for (; s + 1 < s1; s += 2){
    g_load_a<NSUB>(aB, Xb, s+1, dil, rg0, r16, hi);
    g_load_b(bB, wf, s+1, lane, sstride);
    MFMA_SET(aA, bA);
    if (s + 2 < s1){
      g_load_a<NSUB>(aA, Xb, s+2, dil, rg0, r16, hi);
      g_load_b(bA, wf, s+2, lane, sstride);
    }
    MFMA_SET(aB, bB);
  }
  if (s < s1) MFMA_SET(aA, bA);
}

__device__ __forceinline__ void epilogue(f32x4 acc[4][8], u16* Y, const u16* Xc,
    const float* __restrict__ bias, u16* gout, int gstride, int rg0, int r16, int hi){
  #pragma unroll
  for (int g = 0; g < 4; ++g){
    #pragma unroll
    for (int ct = 0; ct < 8; ++ct){
      int oc = ct*16 + r16;
      float bv = bias[oc];
      #pragma unroll
      for (int rr = 0; rr < 4; ++rr){
        int p = rg0 + g*16 + hi*4 + rr;
        float v = acc[g][ct][rr] + bv;
        v = v > 0.f ? v : 0.f;
        int lidx = (p*256 + ((oc*2) ^ ((p & 7) << 4))) >> 1;
        if (Xc) v += b2f(Xc[lidx]);
        u16 hu = f2b(v);
        if (Y) Y[lidx] = hu;
        gout[(size_t)p*gstride + oc] = hu;
      }
    }
  }
}

// ---------------- stage 6: mega conv kernel (head + 7 res) ----------------
// 128 threads = 2 waves; 1 instance per block; LDS ping-pong 2x32KB.
__global__ __launch_bounds__(128) void k_mega(__hip_bfloat16* __restrict__ states_,
    const u16* __restrict__ wfh, const float* __restrict__ bh,
    const u16* __restrict__ wfr, const float* __restrict__ brs){
  __shared__ u16 X[2][16384];
  int t = threadIdx.x, lane = t & 63, wid = t >> 6;
  int r16 = lane & 15, hi = lane >> 4;
  int rg0 = wid*64;
  u16* st = (u16*)states_ + (size_t)blockIdx.x*STROW;
  const bhalf8* WH = (const bhalf8*)wfh;
  const bhalf8* WR = (const bhalf8*)wfr;
  f32x4 acc[4][8];

  // stage z (ch 1024..1120, 12 chunks of 8)
  for (int i = t; i < 2048; i += 128){
    int p = i >> 4, c = i & 15;
    if (c < 12){
      uint4 v = *(const uint4*)(st + (size_t)p*CH + 1024 + c*8);
      *(uint4*)((char*)X[0] + p*256 + ((c*16) ^ ((p & 7) << 4))) = v;
    }
  }
  __syncthreads();

  // head: CI pad 96, K = 9*96, NSUB=3, 27 ksteps, dil=1, out ch 0, no skip
  #pragma unroll
  for (int g = 0; g < 4; ++g)
    #pragma unroll
    for (int ct = 0; ct < 8; ++ct) acc[g][ct] = (f32x4){0.f,0.f,0.f,0.f};
  gemm_run<3>(X[0], WH, 0, 27, 1, rg0, r16, hi, lane, acc, 512);
  epilogue(acc, X[1], nullptr, bh, st, CH, rg0, r16, hi);
  __syncthreads();

  int cur = 1;
  #pragma unroll 1
  for (int l = 0; l < 7; ++l){
    int dil = (l < 3) ? 1 : ((l < 5) ? 2 : 4);
    #pragma unroll
    for (int g = 0; g < 4; ++g)
      #pragma unroll
      for (int ct = 0; ct < 8; ++ct) acc[g][ct] = (f32x4){0.f,0.f,0.f,0.f};
    gemm_run<4>(X[cur], WR + (size_t)l*18432, 0, 36, dil, rg0, r16, hi, lane, acc, 512);
    epilogue(acc, X[cur^1], X[cur], brs + l*128, st + 128*(l+1), CH, rg0, r16, hi);
    __syncthreads();
    cur ^= 1;
  }
}

// ---------------- stage 7: fuse 1x1 (1090->256) MFMA, chunk-staged K ----------------
// 256 threads = 4 waves (2 row-groups x 2 col-groups); single N=256 pass.
__global__ __launch_bounds__(256) void k_fuse(const __hip_bfloat16* __restrict__ states_,
    __hip_bfloat16* __restrict__ fusedb, const u16* __restrict__ wff,
    const float* __restrict__ bfu){
  __shared__ u16 XF[2][16384];
  int t = threadIdx.x, lane = t & 63, wid = t >> 6;
  int r16 = lane & 15, hi = lane >> 4;
  int wr = wid & 1, wc = wid >> 1;
  int rg0 = wr*64;
  const u16* st = (const u16*)states_ + (size_t)blockIdx.x*STROW;
  const bhalf8* WFp = (const bhalf8*)wff + wc*512;
  f32x4 acc[4][8];
  #pragma unroll
  for (int g = 0; g < 4; ++g)
    #pragma unroll
    for (int ct = 0; ct < 8; ++ct) acc[g][ct] = (f32x4){0.f,0.f,0.f,0.f};
  #pragma unroll 1
  for (int cc = 0; cc < 9; ++cc){
    __syncthreads();
    int ch0 = cc*128, nc = (cc == 8) ? 12 : 16;
    for (int i = t; i < 2048; i += 256){
      int p = i >> 4, c = i & 15;
      if (c < nc){
        uint4 v = *(const uint4*)(st + (size_t)p*CH + ch0 + c*8);
        *(uint4*)((char*)XF[cc & 1] + p*256 + ((c*16) ^ ((p & 7) << 4))) = v;
      }
    }
    __syncthreads();
    int s0 = cc*4, s1 = (cc == 8) ? 35 : (s0 + 4);
    gemm_run<4>(XF[cc & 1], WFp, s0, s1, 0, rg0, r16, hi, lane, acc, 1024);
  }
  u16* fo = (u16*)fusedb + (size_t)blockIdx.x*32768 + wc*128;
  epilogue(acc, nullptr, nullptr, bfu + wc*128, fo, 256, rg0, r16, hi);
}

// ---------------- stage 8: p1 (256->64, relu) + p2 (64->2) + pts update ----------------
__global__ __launch_bounds__(128) void k_p1p2(const __hip_bfloat16* __restrict__ fusedbuf,
        const float* __restrict__ wp1r, const float* __restrict__ bp1,
        const float* __restrict__ wp2, const float* __restrict__ bp2,
        float* __restrict__ pts, int base){
  int inst = blockIdx.x, p = threadIdx.x;
  const u16* f = (const u16*)fusedbuf + (size_t)inst*32768 + (size_t)p*256;
  float h[64];
  #pragma unroll
  for (int o = 0; o < 64; ++o) h[o] = bp1[o];
  for (int c8 = 0; c8 < 32; ++c8){
    uint4 v = *(const uint4*)(f + c8*8);
    const u16* vv = (const u16*)&v;
    #pragma unroll
    for (int j = 0; j < 8; ++j){
      float x = b2f(vv[j]);
      const float* w = wp1r + (size_t)(c8*8 + j)*64;
      #pragma unroll
      for (int o = 0; o < 64; ++o) h[o] += w[o]*x;
    }
  }
  float ox = bp2[0], oy = bp2[1];
  #pragma unroll
  for (int o = 0; o < 64; ++o){
    float hv = h[o] > 0.f ? h[o] : 0.f;
    ox += wp2[o]*hv;
    oy += wp2[64+o]*hv;
  }
  int g = base + inst;
  size_t po = ((size_t)g*PPTS + p)*2;
  pts[po]   += ox;
  pts[po+1] += oy;
}

// ---------------- stage 9: mask pts; write valid ----------------
__global__ __launch_bounds__(256) void k_final(float* __restrict__ pts,
        const int* __restrict__ valid_ws, float* __restrict__ valid_out){
  int e = blockIdx.x*256 + threadIdx.x;
  if (e < NINST) valid_out[e] = valid_ws[e] ? 1.f : 0.f;
  if (e < NINST*PPTS){
    float m = valid_ws[e >> 7] ? 1.f : 0.f;
    pts[(size_t)e*2]   *= m;
    pts[(size_t)e*2+1] *= m;
  }
}

// ---------------- weight fragment packs ----------------
// head: [27s][8ct][64l][8] ; K = k*96+ic, NSUB=3; zero for ic>=66
__global__ __launch_bounds__(256) void k_pack_head(const float* __restrict__ w, u16* __restrict__ out){
  int e = blockIdx.x*256 + threadIdx.x;
  if (e >= 110592) return;
  int j = e & 7, l = (e >> 3) & 63, ct = (e >> 9) & 7, s = e >> 12;
  int oc = ct*16 + (l & 15);
  int k = s/3, icq = s - k*3;
  int ic = icq*32 + (l >> 4)*8 + j;
  float v = (ic < 66) ? w[(oc*66 + ic)*9 + k] : 0.f;
  out[e] = f2b(v);
}
// res: per layer [36s][8ct][64l][8] ; K = k*128+ic, NSUB=4
__global__ __launch_bounds__(256) void k_pack_res(const float* __restrict__ w, u16* __restrict__ out){
  int e = blockIdx.x*256 + threadIdx.x;
  if (e >= 1032192) return;
  int lay = e / 147456, r = e - lay*147456;
  int j = r & 7, l = (r >> 3) & 63, ct = (r >> 9) & 7, s = r >> 12;
  int oc = ct*16 + (l & 15);
  int k = s >> 2;
  int ic = (s & 3)*32 + (l >> 4)*8 + j;
  out[e] = f2b(w[((size_t)(lay*128 + oc)*128 + ic)*9 + k]);
}
// fuse: [35s][16ct][64l][8] ; packed ch -> orig: ch<1024 -> 66+ch ; 1024..1089 -> ch-1024 ; else 0
__global__ __launch_bounds__(256) void k_pack_fuse(const float* __restrict__ w, u16* __restrict__ out){
  int e = blockIdx.x*256 + threadIdx.x;
  if (e >= 286720) return;
  int j = e & 7, l = (e >> 3) & 63, ct = (e >> 9) & 15, s = e >> 13;
  int oc = ct*16 + (l & 15);
  int ch = s*32 + (l >> 4)*8 + j;
  float v = 0.f;
  if (ch < 1024) v = w[(size_t)oc*1090 + 66 + ch];
  else if (ch < 1090) v = w[(size_t)oc*1090 + (ch - 1024)];
  out[e] = f2b(v);
}
__global__ __launch_bounds__(256) void k_repack_p1(const float* __restrict__ w, float* __restrict__ wr){
  int e = blockIdx.x*256 + threadIdx.x;
  if (e >= 64*256) return;
  int oc = e / 256, ic = e - oc*256;
  wr[ic*64 + oc] = w[e];
}

extern "C" void kernel_launch(void* const* d_in, const int* in_sizes, int n_in,
                              void* d_out, int out_size, void* d_ws, size_t ws_size,
                              hipStream_t stream){
  (void)in_sizes; (void)n_in; (void)out_size;
  const float* pred   = (const float*)d_in[0];
  const float* feat   = (const float*)d_in[1];
  const float* conv_w = (const float*)d_in[2];
  const float* conv_b = (const float*)d_in[3];
  const float* w_head = (const float*)d_in[4];
  const float* b_head = (const float*)d_in[5];
  const float* w_res  = (const float*)d_in[6];
  const float* b_res  = (const float*)d_in[7];
  const float* w_fuse = (const float*)d_in[8];
  const float* b_fuse = (const float*)d_in[9];
  const float* w_p1   = (const float*)d_in[10];
  const float* b_p1   = (const float*)d_in[11];
  const float* w_p2   = (const float*)d_in[12];
  const float* b_p2   = (const float*)d_in[13];

  float* out = (float*)d_out;
  float* det_out   = out;
  float* ct_out    = out + 28800;
  float* pts_out   = out + 38400;
  float* valid_out = out + 1267200;

  char* wsb = (char*)d_ws;
  size_t woff = 0;
  auto walloc = [&](size_t bytes)->char*{
    char* p = wsb + woff;
    woff += (bytes + 255) & ~(size_t)255;
    return p;
  };
  __hip_bfloat16* cf = (__hip_bfloat16*)walloc((size_t)16*64*160*160*2);
  float* score   = (float*)walloc((size_t)NB*NPRED*4);
  int*   clsb    = (int*)  walloc((size_t)NB*NPRED*4);
  int*   top_i   = (int*)  walloc((size_t)NINST*4);
  float* top_s   = (float*)walloc((size_t)NINST*4);
  float* ct_ws   = (float*)walloc((size_t)NINST*2*4);
  float* half_ws = (float*)walloc((size_t)NINST*2*4);
  int*   valid_ws= (int*)  walloc((size_t)NINST*4);
  u16*   wfh     = (u16*)  walloc((size_t)110592*2);
  u16*   wfr     = (u16*)  walloc((size_t)1032192*2);
  u16*   wff     = (u16*)  walloc((size_t)286720*2);
  float* wr_p1   = (float*)walloc((size_t)16384*4);

  size_t per_inst = (size_t)STROW*2 + (size_t)32768*2;  // states + fused bytes
  long long avail = (long long)ws_size - (long long)woff;
  int C = (int)(avail / (long long)per_inst);
  if (C > NINST) C = NINST;
  if (C < 1) C = 1;
  __hip_bfloat16* states   = (__hip_bfloat16*)walloc((size_t)C*STROW*2);
  __hip_bfloat16* fusedbuf = (__hip_bfloat16*)walloc((size_t)C*32768*2);

  k_pack_head<<<(110592+255)/256, 256, 0, stream>>>(w_head, wfh);
  k_pack_res <<<(1032192+255)/256, 256, 0, stream>>>(w_res, wfr);
  k_pack_fuse<<<(286720+255)/256, 256, 0, stream>>>(w_fuse, wff);
  k_repack_p1<<<(16384+255)/256, 256, 0, stream>>>(w_p1, wr_p1);

  k_score<<<(NB*NPRED+255)/256, 256, 0, stream>>>(pred, score, clsb);
  k_topk <<<NB, 1024, 0, stream>>>(score, top_i, top_s);
  k_nms  <<<NB, 384, 0, stream>>>(pred, top_i, top_s, clsb, det_out, ct_out, pts_out,
                                  ct_ws, half_ws, valid_ws);
  k_cnn  <<<dim3(16,100), 256, 0, stream>>>(feat, conv_w, conv_b, cf);

  for (int it = 0; it < 2; ++it){
    for (int base = 0; base < NINST; base += C){
      int cnt = NINST - base; if (cnt > C) cnt = C;
      k_sample<<<(cnt*PPTS+255)/256, 256, 0, stream>>>(cf, pts_out, ct_ws, half_ws, states, base, cnt);
      k_mega<<<cnt, 128, 0, stream>>>(states, wfh, b_head, wfr, b_res);
      k_fuse<<<cnt, 256, 0, stream>>>(states, fusedbuf, wff, b_fuse);
      k_p1p2<<<cnt, 128, 0, stream>>>(fusedbuf, wr_p1, b_p1, w_p2, b_p2, pts_out, base);
    }
  }
  k_final<<<(NINST*PPTS+255)/256, 256, 0, stream>>>(pts_out, valid_ws, valid_out);
}

// Round 6
// 10152.161 us; speedup vs baseline: 5.0814x; 1.0708x over previous
//
#include <hip/hip_runtime.h>
#include <hip/hip_bf16.h>
#include <math.h>

typedef unsigned int u32;
typedef unsigned long long u64;
typedef unsigned short u16;

#define NB 16
#define NPRED 25200
#define ND 85
#define NCLS 80
#define KDET 300
#define PPTS 128
#define NINST (NB*KDET)
#define CONF_T 0.2f
#define IOU_T 0.3f
#define MAX_WH_ 4096.0f
#define NBKT 8192

// slab layout per block: [p=128][ch=1120] bf16
//   ch 0..127     : head conv output   (orig fuse ch 66..193)
//   ch 128*(l+1)  : res block l output (orig 194+128l ..)
//   ch 1024..1089 : z = [feats(64), relx, rely] (orig 0..65)
//   ch 1090..1119 : pad (zero weights)
#define CH 1120
#define STROW 143360   // u16 per block slab

typedef __attribute__((ext_vector_type(8))) short bhalf8;
typedef __attribute__((ext_vector_type(4))) float f32x4;

__device__ __forceinline__ float b2f(u16 u){ return __uint_as_float((u32)u << 16); }
__device__ __forceinline__ u16 f2b(float v){ __hip_bfloat16 h = __float2bfloat16(v); return *(u16*)&h; }
#define SWZ(p) (((p)&7)<<4)

// ---------------- stage 1: per-box score & class ----------------
__global__ __launch_bounds__(256) void k_score(const float* __restrict__ pred,
        float* __restrict__ score, int* __restrict__ cls){
  int i = blockIdx.x*256 + threadIdx.x;
  if (i >= NB*NPRED) return;
  const float* r = pred + (size_t)i*ND;
  float obj = r[4];
  float best = obj*r[5]; int bc = 0;
  for (int c = 1; c < NCLS; ++c){
    float v = obj*r[5+c];
    if (v > best){ best = v; bc = c; }
  }
  score[i] = (best > CONF_T) ? best : 0.f;
  cls[i] = bc;
}

// ---------------- stage 2: exact top-300 per batch ----------------
__global__ __launch_bounds__(1024) void k_topk(const float* __restrict__ score,
        int* __restrict__ top_i, float* __restrict__ top_s){
  __shared__ int hist[NBKT];
  __shared__ int part[1024];
  __shared__ u64 keys[1024];
  __shared__ int s_bstar, s_cnt;
  int b = blockIdx.x, t = threadIdx.x;
  const float* s = score + (size_t)b*NPRED;
  for (int i = t; i < NBKT; i += 1024) hist[i] = 0;
  __syncthreads();
  for (int i = t; i < NPRED; i += 1024){
    float v = s[i];
    if (v > 0.f){
      int bk = (int)(v * (float)NBKT); if (bk > NBKT-1) bk = NBKT-1;
      atomicAdd(&hist[bk], 1);
    }
  }
  __syncthreads();
  int psum = 0;
  for (int j = 0; j < 8; ++j) psum += hist[t*8+j];
  part[t] = psum;
  __syncthreads();
  if (t == 0){
    int cum = 0, bstar = 0;
    for (int q = 1023; q >= 0; --q){
      if (cum + part[q] >= KDET){
        int c2 = cum; int bb;
        for (bb = q*8+7; bb >= q*8; --bb){
          c2 += hist[bb];
          if (c2 >= KDET) break;
        }
        if (bb < q*8) bb = q*8;
        bstar = bb;
        break;
      }
      cum += part[q];
    }
    s_bstar = bstar;
    s_cnt = 0;
  }
  keys[t] = 0ull;
  __syncthreads();
  int bstar = s_bstar;
  for (int i = t; i < NPRED; i += 1024){
    float v = s[i];
    if (v > 0.f){
      int bk = (int)(v * (float)NBKT); if (bk > NBKT-1) bk = NBKT-1;
      if (bk >= bstar){
        int pos = atomicAdd(&s_cnt, 1);
        if (pos < 1024){
          keys[pos] = ((u64)__float_as_uint(v) << 32) | (u32)(~(u32)i);
        }
      }
    }
  }
  __syncthreads();
  for (int k = 2; k <= 1024; k <<= 1){
    for (int j = k>>1; j > 0; j >>= 1){
      int ixj = t ^ j;
      if (ixj > t){
        u64 a = keys[t], c = keys[ixj];
        bool up = ((t & k) == 0);
        bool sw = up ? (a < c) : (a > c);
        if (sw){ keys[t] = c; keys[ixj] = a; }
      }
      __syncthreads();
    }
  }
  if (t < KDET){
    u64 key = keys[t];
    float v; int idx;
    if (key == 0ull){ v = 0.f; idx = 0; }
    else { v = __uint_as_float((u32)(key >> 32)); idx = (int)(~(u32)(key & 0xffffffffull)); }
    top_s[b*KDET + t] = v;
    top_i[b*KDET + t] = idx;
  }
}

// ---------------- stage 3: NMS + box geometry + pts init ----------------
__global__ __launch_bounds__(384) void k_nms(const float* __restrict__ pred,
        const int* __restrict__ top_i, const float* __restrict__ top_s,
        const int* __restrict__ clsb,
        float* __restrict__ det_out, float* __restrict__ ct_out, float* __restrict__ pts_out,
        float* __restrict__ ct_ws, float* __restrict__ half_ws, int* __restrict__ valid_ws){
  __shared__ float bx0[KDET], bx1[KDET], bx2[KDET], bx3[KDET], ar[KDET];
  __shared__ float rx0[KDET], rx1[KDET], rx2[KDET], rx3[KDET];
  __shared__ float sc[KDET], cl[KDET];
  __shared__ float ctxs[KDET], ctys[KDET], hxs[KDET], hys[KDET];
  __shared__ int keep[KDET];
  int b = blockIdx.x, t = threadIdx.x;
  for (int i = t; i < KDET; i += 384){
    int idx = top_i[b*KDET + i];
    const float* r = pred + ((size_t)b*NPRED + idx)*ND;
    float cx = r[0], cy = r[1], w = r[2], h = r[3];
    float x1 = cx - w/2.f, y1 = cy - h/2.f, x2 = cx + w/2.f, y2 = cy + h/2.f;
    float c = (float)clsb[(size_t)b*NPRED + idx];
    float o = c * MAX_WH_;
    float a0 = x1 + o, a1 = y1 + o, a2 = x2 + o, a3 = y2 + o;
    bx0[i]=a0; bx1[i]=a1; bx2[i]=a2; bx3[i]=a3;
    ar[i] = (a2-a0)*(a3-a1);
    rx0[i]=x1; rx1[i]=y1; rx2[i]=x2; rx3[i]=y2;
    sc[i] = top_s[b*KDET + i];
    cl[i] = c;
    keep[i] = 1;
  }
  __syncthreads();
  for (int i = 0; i < KDET; ++i){
    if (keep[i]){
      float b0=bx0[i], b1=bx1[i], b2=bx2[i], b3=bx3[i], ai=ar[i];
      for (int j = i+1+t; j < KDET; j += 384){
        float ltx = fmaxf(b0, bx0[j]);
        float lty = fmaxf(b1, bx1[j]);
        float rbx = fminf(b2, bx2[j]);
        float rby = fminf(b3, bx3[j]);
        float ww = rbx - ltx; ww = ww > 0.f ? ww : 0.f;
        float hh = rby - lty; hh = hh > 0.f ? hh : 0.f;
        float inter = ww*hh;
        float iou = inter / (ai + ar[j] - inter + 1e-9f);
        if (iou > IOU_T) keep[j] = 0;
      }
    }
    __syncthreads();
  }
  for (int i = t; i < KDET; i += 384){
    int v = (keep[i] && (sc[i] > CONF_T)) ? 1 : 0;
    valid_ws[b*KDET + i] = v;
    size_t o6 = ((size_t)b*KDET + i)*6;
    det_out[o6+0]=rx0[i]; det_out[o6+1]=rx1[i]; det_out[o6+2]=rx2[i]; det_out[o6+3]=rx3[i];
    det_out[o6+4]=sc[i];  det_out[o6+5]=cl[i];
    float bd0 = rx0[i]/4.f, bd1 = rx1[i]/4.f, bd2 = rx2[i]/4.f, bd3 = rx3[i]/4.f;
    float cx = (bd0+bd2)/2.f, cy = (bd1+bd3)/2.f;
    float hx = (bd2-bd0)/2.f; hx = hx > 1e-3f ? hx : 1e-3f;
    float hy = (bd3-bd1)/2.f; hy = hy > 1e-3f ? hy : 1e-3f;
    ct_out[((size_t)b*KDET+i)*2+0] = cx;
    ct_out[((size_t)b*KDET+i)*2+1] = cy;
    ct_ws[((size_t)b*KDET+i)*2+0] = cx;
    ct_ws[((size_t)b*KDET+i)*2+1] = cy;
    half_ws[((size_t)b*KDET+i)*2+0] = hx;
    half_ws[((size_t)b*KDET+i)*2+1] = hy;
    ctxs[i]=cx; ctys[i]=cy; hxs[i]=hx; hys[i]=hy;
  }
  __syncthreads();
  for (int e = t; e < KDET*PPTS; e += 384){
    int i = e >> 7, p = e & 127;
    float th = (float)p * 0.04908738521234052f;
    size_t o = ((size_t)(b*KDET + i)*PPTS + p)*2;
    pts_out[o+0] = ctxs[i] + hxs[i]*cosf(th);
    pts_out[o+1] = ctys[i] + hys[i]*sinf(th);
  }
}

// ---------------- stage 4: upsample2x + 3x3 conv + SiLU -> cf (bf16) ----------------
// 8x8 output tile; 256 thr = 4 oc-groups(16) x 64 px; acc[16] reg-resident.
__global__ __launch_bounds__(256) void k_cnn(const float* __restrict__ feat,
        const float* __restrict__ cw, const float* __restrict__ cb,
        __hip_bfloat16* __restrict__ cf){
  __shared__ float up[2][120];   // [ic-pair][10*12]
  int b = blockIdx.x, tile = blockIdx.y;
  int ty0 = (tile/20)*8, tx0 = (tile - (tile/20)*20)*8;
  int t = threadIdx.x;
  int og = t >> 6, lane = t & 63;
  int py = lane >> 3, px = lane & 7;
  float acc[16];
  #pragma unroll
  for (int oo = 0; oo < 16; ++oo) acc[oo] = 0.f;
  #pragma unroll 1
  for (int ic = 0; ic < 128; ic += 2){
    __syncthreads();
    if (t < 200){
      int which = t/100, u = t - which*100;
      int r = u/10, cix = u - r*10;
      int uy = ty0 - 1 + r, ux = tx0 - 1 + cix;
      float val = 0.f;
      if (uy >= 0 && uy < 160 && ux >= 0 && ux < 160){
        const float* fin = feat + ((size_t)b*128 + ic + which)*6400;
        float cyf = 0.5f*(float)uy - 0.25f;
        float cxf = 0.5f*(float)ux - 0.25f;
        float fy0 = floorf(cyf), fx0 = floorf(cxf);
        float fy = cyf - fy0, fx = cxf - fx0;
        int y0 = (int)fy0, x0 = (int)fx0;
        int y0c = y0 < 0 ? 0 : (y0 > 79 ? 79 : y0);
        int y1c = y0+1 > 79 ? 79 : (y0+1 < 0 ? 0 : y0+1);
        int x0c = x0 < 0 ? 0 : (x0 > 79 ? 79 : x0);
        int x1c = x0+1 > 79 ? 79 : (x0+1 < 0 ? 0 : x0+1);
        float v00 = fin[y0c*80+x0c], v01 = fin[y0c*80+x1c];
        float v10 = fin[y1c*80+x0c], v11 = fin[y1c*80+x1c];
        val = v00*(1.f-fy)*(1.f-fx) + v01*(1.f-fy)*fx + v10*fy*(1.f-fx) + v11*fy*fx;
      }
      up[which][r*12 + cix] = val;
    }
    __syncthreads();
    #pragma unroll
    for (int which = 0; which < 2; ++which){
      float v[9];
      #pragma unroll
      for (int k = 0; k < 9; ++k)
        v[k] = up[which][(py + k/3)*12 + (px + k%3)];
      #pragma unroll
      for (int oo = 0; oo < 16; ++oo){
        const float* w9 = cw + ((size_t)(og*16 + oo)*128 + ic + which)*9;
        float a = acc[oo];
        #pragma unroll
        for (int k = 0; k < 9; ++k) a += w9[k]*v[k];
        acc[oo] = a;
      }
    }
  }
  int oy = ty0 + py, ox = tx0 + px;
  #pragma unroll
  for (int oo = 0; oo < 16; ++oo){
    int oc = og*16 + oo;
    float x = acc[oo] + cb[oc];
    float sg = 1.f / (1.f + __expf(-x));
    cf[((size_t)b*64 + oc)*25600 + (size_t)oy*160 + ox] = __float2bfloat16(x*sg);
  }
}

// ================= MFMA GEMM core =================
template<int NSUB>
__device__ __forceinline__ void g_load_a(bhalf8* dst, const u16* Xb, int s, int dil,
                                         int rg0, int r16, int hi){
  int k = s / NSUB;
  int icb = (s - k*NSUB)*64 + hi*16;
  int shift = (k - 4)*dil;
  #pragma unroll
  for (int g = 0; g < 4; ++g){
    int row = (rg0 + g*16 + r16 + shift + 128) & 127;
    dst[g] = *(const bhalf8*)((const char*)Xb + row*256 + (icb ^ SWZ(row)));
  }
}
template<int NCT>
__device__ __forceinline__ void g_load_b(bhalf8* dst, const bhalf8* wf, int s, int ctbase,
                                         int lane, int sstride){
  const bhalf8* w = wf + (size_t)s*sstride + ctbase*64 + lane;
  #pragma unroll
  for (int ct = 0; ct < NCT; ++ct) dst[ct] = w[ct*64];
}

template<int NSUB, int NCT, bool DBUF>
__device__ __forceinline__ void gemm_run(const u16* Xb, const bhalf8* wf, int s0, int s1,
    int dil, int rg0, int ctbase, int r16, int hi, int lane, f32x4 (&acc)[4][NCT], int sstride){
  if (DBUF){
    bhalf8 aA[4], bA[NCT], aB[4], bB[NCT];
    g_load_a<NSUB>(aA, Xb, s0, dil, rg0, r16, hi);
    g_load_b<NCT>(bA, wf, s0, ctbase, lane, sstride);
    int s = s0;
    for (; s + 1 < s1; s += 2){
      g_load_a<NSUB>(aB, Xb, s+1, dil, rg0, r16, hi);
      g_load_b<NCT>(bB, wf, s+1, ctbase, lane, sstride);
      #pragma unroll
      for (int g = 0; g < 4; ++g)
        #pragma unroll
        for (int ct = 0; ct < NCT; ++ct)
          acc[g][ct] = __builtin_amdgcn_mfma_f32_16x16x32_bf16(aA[g], bA[ct], acc[g][ct], 0, 0, 0);
      if (s + 2 < s1){
        g_load_a<NSUB>(aA, Xb, s+2, dil, rg0, r16, hi);
        g_load_b<NCT>(bA, wf, s+2, ctbase, lane, sstride);
      }
      #pragma unroll
      for (int g = 0; g < 4; ++g)
        #pragma unroll
        for (int ct = 0; ct < NCT; ++ct)
          acc[g][ct] = __builtin_amdgcn_mfma_f32_16x16x32_bf16(aB[g], bB[ct], acc[g][ct], 0, 0, 0);
    }
    if (s < s1){
      #pragma unroll
      for (int g = 0; g < 4; ++g)
        #pragma unroll
        for (int ct = 0; ct < NCT; ++ct)
          acc[g][ct] = __builtin_amdgcn_mfma_f32_16x16x32_bf16(aA[g], bA[ct], acc[g][ct], 0, 0, 0);
    }
  } else {
    for (int s = s0; s < s1; ++s){
      bhalf8 a[4], bb[NCT];
      g_load_a<NSUB>(a, Xb, s, dil, rg0, r16, hi);
      g_load_b<NCT>(bb, wf, s, ctbase, lane, sstride);
      #pragma unroll
      for (int g = 0; g < 4; ++g)
        #pragma unroll
        for (int ct = 0; ct < NCT; ++ct)
          acc[g][ct] = __builtin_amdgcn_mfma_f32_16x16x32_bf16(a[g], bb[ct], acc[g][ct], 0, 0, 0);
    }
  }
}

// ---------------- stage 5: merged snake kernel ----------------
// 256 thr = 4 waves (2 row-halves x 2 col-halves); grid-stride over instances;
// per-block slab in global ws; both snake iterations in-kernel.
__global__ __launch_bounds__(256, 2) void k_snake(const __hip_bfloat16* __restrict__ cf_,
    float* __restrict__ pts, const float* __restrict__ ct_ws, const float* __restrict__ half_ws,
    u16* __restrict__ slabg,
    const u16* __restrict__ wfh, const float* __restrict__ bh,
    const u16* __restrict__ wfr, const float* __restrict__ brs,
    const u16* __restrict__ wff, const float* __restrict__ bfu,
    const u16* __restrict__ wp1f, const float* __restrict__ bp1,
    const float* __restrict__ wp2, const float* __restrict__ bp2){
  __shared__ u16 X[2][16384];
  __shared__ float pxy[128][2];
  int t = threadIdx.x, lane = t & 63, wid = t >> 6;
  int r16 = lane & 15, hi = lane >> 4;
  int wr = wid & 1, wc = wid >> 1;
  int rgM = wr*64;          // rows for mega/fuse/p1
  u16* slab = slabg + (size_t)blockIdx.x * STROW;
  const bhalf8* WH = (const bhalf8*)wfh;
  const bhalf8* WR = (const bhalf8*)wfr;
  const bhalf8* WF = (const bhalf8*)wff;
  const bhalf8* WP = (const bhalf8*)wp1f;
  const u16* cfu = (const u16*)cf_;

  #pragma unroll 1
  for (int inst = blockIdx.x; inst < NINST; inst += gridDim.x){
    if (t < 128){
      pxy[t][0] = pts[(size_t)inst*256 + t*2];
      pxy[t][1] = pts[(size_t)inst*256 + t*2 + 1];
    }
    float ctx = ct_ws[inst*2], cty = ct_ws[inst*2+1];
    float hx = half_ws[inst*2], hy = half_ws[inst*2+1];
    int bimg = inst / KDET;

    #pragma unroll 1
    for (int iter = 0; iter < 2; ++iter){
      __syncthreads();   // pxy current; X free
      // ---- sample: z -> X[0] (swizzled) + slab z copy ----
      {
        int p = t & 127, hf = t >> 7;
        float px = pxy[p][0], py = pxy[p][1];
        float x = px < 0.f ? 0.f : (px > 159.f ? 159.f : px);
        float y = py < 0.f ? 0.f : (py > 159.f ? 159.f : py);
        float x0f = floorf(x); x0f = x0f < 0.f ? 0.f : (x0f > 158.f ? 158.f : x0f);
        float y0f = floorf(y); y0f = y0f < 0.f ? 0.f : (y0f > 158.f ? 158.f : y0f);
        float dx = x - x0f, dy = y - y0f;
        int x0 = (int)x0f, y0 = (int)y0f;
        float w00 = (1.f-dx)*(1.f-dy), w01 = dx*(1.f-dy), w10 = (1.f-dx)*dy, w11 = dx*dy;
        const u16* f = cfu + (size_t)bimg*64*25600 + (size_t)y0*160 + x0;
        __align__(16) u16 zl[32];
        for (int c = 0; c < 32; ++c){
          const u16* fc = f + (size_t)(hf*32 + c)*25600;
          float v00 = b2f(fc[0]), v01 = b2f(fc[1]);
          float v10 = b2f(fc[160]), v11 = b2f(fc[161]);
          zl[c] = f2b(v00*w00 + v01*w01 + v10*w10 + v11*w11);
        }
        char* xrow = (char*)X[0] + p*256;
        u16* zs = slab + (size_t)p*CH + 1024 + hf*32;
        #pragma unroll
        for (int q = 0; q < 4; ++q){
          *(uint4*)(xrow + ((hf*64 + q*16) ^ SWZ(p))) = ((const uint4*)zl)[q];
          *(uint4*)(zs + q*8) = ((const uint4*)zl)[q];
        }
        uint4 z4; z4.x = 0; z4.y = 0; z4.z = 0; z4.w = 0;
        if (hf == 0){
          __align__(16) u16 ex[8];
          ex[0] = f2b((px - ctx)/hx); ex[1] = f2b((py - cty)/hy);
          #pragma unroll
          for (int j = 2; j < 8; ++j) ex[j] = 0;
          *(uint4*)(xrow + (128 ^ SWZ(p))) = *(const uint4*)ex;
          *(uint4*)(slab + (size_t)p*CH + 1088) = *(const uint4*)ex;
        } else {
          *(uint4*)(xrow + (144 ^ SWZ(p))) = z4;
          *(uint4*)(xrow + (160 ^ SWZ(p))) = z4;
          *(uint4*)(xrow + (176 ^ SWZ(p))) = z4;
          *(uint4*)(slab + (size_t)p*CH + 1096) = z4;
          *(uint4*)(slab + (size_t)p*CH + 1104) = z4;
          *(uint4*)(slab + (size_t)p*CH + 1112) = z4;
        }
      }
      __syncthreads();
      // ---- head + 7 res layers ----
      int cur = 0;
      #pragma unroll 1
      for (int l = -1; l < 7; ++l){
        f32x4 acc[4][4];
        #pragma unroll
        for (int g = 0; g < 4; ++g)
          #pragma unroll
          for (int ct = 0; ct < 4; ++ct) acc[g][ct] = (f32x4){0.f,0.f,0.f,0.f};
        const float* bias;
        u16* slout;
        if (l < 0){
          gemm_run<3,4,true>(X[0], WH, 0, 27, 1, rgM, wc*4, r16, hi, lane, acc, 512);
          bias = bh; slout = slab;
        } else {
          int dil = (l < 3) ? 1 : ((l < 5) ? 2 : 4);
          gemm_run<4,4,true>(X[cur], WR + (size_t)l*18432, 0, 36, dil, rgM, wc*4, r16, hi, lane, acc, 512);
          bias = brs + l*128; slout = slab + 128*(l+1);
        }
        // epilogue: relu(+skip) -> X[cur^1] + slab
        u16* Y = X[cur^1];
        const u16* Xc = (l < 0) ? nullptr : X[cur];
        #pragma unroll
        for (int g = 0; g < 4; ++g){
          #pragma unroll
          for (int ct = 0; ct < 4; ++ct){
            int oc = (wc*4 + ct)*16 + r16;
            float bv = bias[oc];
            #pragma unroll
            for (int rr = 0; rr < 4; ++rr){
              int p = rgM + g*16 + hi*4 + rr;
              float v = acc[g][ct][rr] + bv;
              v = v > 0.f ? v : 0.f;
              int lidx = (p*256 + ((oc*2) ^ SWZ(p))) >> 1;
              if (Xc) v += b2f(Xc[lidx]);
              u16 hu = f2b(v);
              Y[lidx] = hu;
              slout[(size_t)p*CH + oc] = hu;
            }
          }
        }
        __syncthreads();
        cur ^= 1;
      }
      // ---- fuse (1120 -> 256), chunk-staged from slab ----
      {
        f32x4 acc[4][8];
        #pragma unroll
        for (int g = 0; g < 4; ++g)
          #pragma unroll
          for (int ct = 0; ct < 8; ++ct) acc[g][ct] = (f32x4){0.f,0.f,0.f,0.f};
        #pragma unroll 1
        for (int cc = 0; cc < 9; ++cc){
          __syncthreads();
          int ch0 = cc*128, nc = (cc == 8) ? 12 : 16;
          for (int i = t; i < 2048; i += 256){
            int p = i >> 4, c = i & 15;
            if (c < nc){
              uint4 v = *(const uint4*)(slab + (size_t)p*CH + ch0 + c*8);
              *(uint4*)((char*)X[cc & 1] + p*256 + ((c*16) ^ SWZ(p))) = v;
            }
          }
          __syncthreads();
          int s0 = cc*4, s1 = (cc == 8) ? 35 : (s0 + 4);
          gemm_run<4,8,false>(X[cc & 1], WF, s0, s1, 0, rgM, wc*8, r16, hi, lane, acc, 1024);
        }
        __syncthreads();
        // epilogue: relu -> X[0](oc 0..127) / X[1](oc 128..255)
        #pragma unroll
        for (int g = 0; g < 4; ++g){
          #pragma unroll
          for (int ct = 0; ct < 8; ++ct){
            int ocg = (wc*8 + ct)*16 + r16;
            float bv = bfu[ocg];
            u16* Yb = X[ocg >> 7];
            int col = ocg & 127;
            #pragma unroll
            for (int rr = 0; rr < 4; ++rr){
              int p = rgM + g*16 + hi*4 + rr;
              float v = acc[g][ct][rr] + bv;
              v = v > 0.f ? v : 0.f;
              Yb[(p*256 + ((col*2) ^ SWZ(p))) >> 1] = f2b(v);
            }
          }
        }
      }
      __syncthreads();
      // ---- p1 (256->64) MFMA ----
      {
        f32x4 acc[4][2];
        #pragma unroll
        for (int g = 0; g < 4; ++g)
          #pragma unroll
          for (int ct = 0; ct < 2; ++ct) acc[g][ct] = (f32x4){0.f,0.f,0.f,0.f};
        gemm_run<4,2,true>(X[0], WP, 0, 4, 0, rgM, wc*2, r16, hi, lane, acc, 256);
        gemm_run<4,2,true>(X[1], WP, 4, 8, 0, rgM, wc*2, r16, hi, lane, acc, 256);
        __syncthreads();
        // h = relu(acc + b1) -> X[0] cols 0..63
        #pragma unroll
        for (int g = 0; g < 4; ++g){
          #pragma unroll
          for (int ct = 0; ct < 2; ++ct){
            int oc = (wc*2 + ct)*16 + r16;
            float bv = bp1[oc];
            #pragma unroll
            for (int rr = 0; rr < 4; ++rr){
              int p = rgM + g*16 + hi*4 + rr;
              float v = acc[g][ct][rr] + bv;
              v = v > 0.f ? v : 0.f;
              X[0][(p*256 + ((oc*2) ^ SWZ(p))) >> 1] = f2b(v);
            }
          }
        }
      }
      __syncthreads();
      // ---- p2 (64->2) + pts update ----
      if (t < 128){
        int p = t;
        float ox = bp2[0], oy = bp2[1];
        #pragma unroll
        for (int j8 = 0; j8 < 8; ++j8){
          uint4 u = *(const uint4*)((const char*)X[0] + p*256 + ((j8*16) ^ SWZ(p)));
          __align__(16) u16 hh[8];
          *(uint4*)hh = u;
          #pragma unroll
          for (int j = 0; j < 8; ++j){
            float hv = b2f(hh[j]);
            int oc = j8*8 + j;
            ox += wp2[oc]*hv;
            oy += wp2[64 + oc]*hv;
          }
        }
        pxy[p][0] += ox;
        pxy[p][1] += oy;
      }
    }
    if (t < 128){
      pts[(size_t)inst*256 + t*2]     = pxy[t][0];
      pts[(size_t)inst*256 + t*2 + 1] = pxy[t][1];
    }
  }
}

// ---------------- stage 9: mask pts; write valid ----------------
__global__ __launch_bounds__(256) void k_final(float* __restrict__ pts,
        const int* __restrict__ valid_ws, float* __restrict__ valid_out){
  int e = blockIdx.x*256 + threadIdx.x;
  if (e < NINST) valid_out[e] = valid_ws[e] ? 1.f : 0.f;
  if (e < NINST*PPTS){
    float m = valid_ws[e >> 7] ? 1.f : 0.f;
    pts[(size_t)e*2]   *= m;
    pts[(size_t)e*2+1] *= m;
  }
}

// ---------------- weight fragment packs ----------------
__global__ __launch_bounds__(256) void k_pack_head(const float* __restrict__ w, u16* __restrict__ out){
  int e = blockIdx.x*256 + threadIdx.x;
  if (e >= 110592) return;
  int j = e & 7, l = (e >> 3) & 63, ct = (e >> 9) & 7, s = e >> 12;
  int oc = ct*16 + (l & 15);
  int k = s/3, icq = s - k*3;
  int ic = icq*32 + (l >> 4)*8 + j;
  float v = (ic < 66) ? w[(oc*66 + ic)*9 + k] : 0.f;
  out[e] = f2b(v);
}
__global__ __launch_bounds__(256) void k_pack_res(const float* __restrict__ w, u16* __restrict__ out){
  int e = blockIdx.x*256 + threadIdx.x;
  if (e >= 1032192) return;
  int lay = e / 147456, r = e - lay*147456;
  int j = r & 7, l = (r >> 3) & 63, ct = (r >> 9) & 7, s = r >> 12;
  int oc = ct*16 + (l & 15);
  int k = s >> 2;
  int ic = (s & 3)*32 + (l >> 4)*8 + j;
  out[e] = f2b(w[((size_t)(lay*128 + oc)*128 + ic)*9 + k]);
}
__global__ __launch_bounds__(256) void k_pack_fuse(const float* __restrict__ w, u16* __restrict__ out){
  int e = blockIdx.x*256 + threadIdx.x;
  if (e >= 286720) return;
  int j = e & 7, l = (e >> 3) & 63, ct = (e >> 9) & 15, s = e >> 13;
  int oc = ct*16 + (l & 15);
  int ch = s*32 + (l >> 4)*8 + j;
  float v = 0.f;
  if (ch < 1024) v = w[(size_t)oc*1090 + 66 + ch];
  else if (ch < 1090) v = w[(size_t)oc*1090 + (ch - 1024)];
  out[e] = f2b(v);
}
// p1: [8s][4ct][64l][8] ; K(ic) = s*32 + (l>>4)*8 + j ; oc = ct*16 + (l&15)
__global__ __launch_bounds__(256) void k_pack_p1(const float* __restrict__ w, u16* __restrict__ out){
  int e = blockIdx.x*256 + threadIdx.x;
  if (e >= 16384) return;
  int j = e & 7, l = (e >> 3) & 63, ct = (e >> 9) & 3, s = e >> 11;
  int oc = ct*16 + (l & 15);
  int ic = s*32 + (l >> 4)*8 + j;
  out[e] = f2b(w[oc*256 + ic]);
}

extern "C" void kernel_launch(void* const* d_in, const int* in_sizes, int n_in,
                              void* d_out, int out_size, void* d_ws, size_t ws_size,
                              hipStream_t stream){
  (void)in_sizes; (void)n_in; (void)out_size;
  const float* pred   = (const float*)d_in[0];
  const float* feat   = (const float*)d_in[1];
  const float* conv_w = (const float*)d_in[2];
  const float* conv_b = (const float*)d_in[3];
  const float* w_head = (const float*)d_in[4];
  const float* b_head = (const float*)d_in[5];
  const float* w_res  = (const float*)d_in[6];
  const float* b_res  = (const float*)d_in[7];
  const float* w_fuse = (const float*)d_in[8];
  const float* b_fuse = (const float*)d_in[9];
  const float* w_p1   = (const float*)d_in[10];
  const float* b_p1   = (const float*)d_in[11];
  const float* w_p2   = (const float*)d_in[12];
  const float* b_p2   = (const float*)d_in[13];

  float* out = (float*)d_out;
  float* det_out   = out;
  float* ct_out    = out + 28800;
  float* pts_out   = out + 38400;
  float* valid_out = out + 1267200;

  char* wsb = (char*)d_ws;
  size_t woff = 0;
  auto walloc = [&](size_t bytes)->char*{
    char* p = wsb + woff;
    woff += (bytes + 255) & ~(size_t)255;
    return p;
  };
  __hip_bfloat16* cf = (__hip_bfloat16*)walloc((size_t)16*64*160*160*2);
  float* score   = (float*)walloc((size_t)NB*NPRED*4);
  int*   clsb    = (int*)  walloc((size_t)NB*NPRED*4);
  int*   top_i   = (int*)  walloc((size_t)NINST*4);
  float* top_s   = (float*)walloc((size_t)NINST*4);
  float* ct_ws   = (float*)walloc((size_t)NINST*2*4);
  float* half_ws = (float*)walloc((size_t)NINST*2*4);
  int*   valid_ws= (int*)  walloc((size_t)NINST*4);
  u16*   wfh     = (u16*)  walloc((size_t)110592*2);
  u16*   wfr     = (u16*)  walloc((size_t)1032192*2);
  u16*   wff     = (u16*)  walloc((size_t)286720*2);
  u16*   wp1f    = (u16*)  walloc((size_t)16384*2);

  long long avail = (long long)ws_size - (long long)woff;
  int G = (int)(avail / (long long)(STROW*2));
  if (G > 1024) G = 1024;
  if (G > NINST) G = NINST;
  if (G < 1) G = 1;
  u16* slabg = (u16*)walloc((size_t)G*STROW*2);

  k_pack_head<<<(110592+255)/256, 256, 0, stream>>>(w_head, wfh);
  k_pack_res <<<(1032192+255)/256, 256, 0, stream>>>(w_res, wfr);
  k_pack_fuse<<<(286720+255)/256, 256, 0, stream>>>(w_fuse, wff);
  k_pack_p1  <<<(16384+255)/256, 256, 0, stream>>>(w_p1, wp1f);

  k_score<<<(NB*NPRED+255)/256, 256, 0, stream>>>(pred, score, clsb);
  k_topk <<<NB, 1024, 0, stream>>>(score, top_i, top_s);
  k_nms  <<<NB, 384, 0, stream>>>(pred, top_i, top_s, clsb, det_out, ct_out, pts_out,
                                  ct_ws, half_ws, valid_ws);
  k_cnn  <<<dim3(16,400), 256, 0, stream>>>(feat, conv_w, conv_b, cf);

  k_snake<<<G, 256, 0, stream>>>(cf, pts_out, ct_ws, half_ws, slabg,
                                 wfh, b_head, wfr, b_res, wff, b_fuse,
                                 wp1f, b_p1, w_p2, b_p2);

  k_final<<<(NINST*PPTS+255)/256, 256, 0, stream>>>(pts_out, valid_ws, valid_out);
}